// Round 1
// baseline (452.215 us; speedup 1.0000x reference)
//
#include <hip/hip_runtime.h>
#include <hip/hip_bf16.h>

typedef __hip_bfloat16 bf16;
typedef short bf16x8 __attribute__((ext_vector_type(8)));   // 8 bf16 = 4 VGPRs (MFMA frag)
typedef float f32x4 __attribute__((ext_vector_type(4)));
typedef short s4 __attribute__((ext_vector_type(4)));

#define LL 2048
#define SS 2048
#define EE 1024
#define HH 16
#define HD 64
#define MM (LL * 2)   // 4096 rows (l*B+b)

static __device__ __forceinline__ short f2bs(float f) {
  bf16 h = __float2bfloat16(f);
  short u;
  __builtin_memcpy(&u, &h, 2);
  return u;
}

// async global->LDS, 16B per lane. LDS dest must be wave-uniform base + lane*16.
#define GLL16(gp, lp) __builtin_amdgcn_global_load_lds(                        \
    (const __attribute__((address_space(1))) void*)(gp),                       \
    (__attribute__((address_space(3))) void*)(lp), 16, 0, 0)

// cos/sin table: tab[pos*32 + fi] = {cos(pos*invfreq[fi]), sin(...)}
__global__ __launch_bounds__(256) void rope_table_kernel(float2* __restrict__ tab) {
  int i = blockIdx.x * 256 + threadIdx.x;     // 2048*32 entries
  int pos = i >> 5, fi = i & 31;
  float freq = expf(-(float)fi * (9.210340371976184f / 32.0f));  // 10000^(-fi/32)
  float ang = (float)pos * freq;
  float s, c;
  sincosf(ang, &s, &c);
  tab[i] = make_float2(c, s);
}

// mask byte -> additive float bias (-1e30 masked, 0 else). B*S = 4096 entries.
__global__ void maskf_kernel(const unsigned char* __restrict__ m,
                             float* __restrict__ mf) {
  int i = blockIdx.x * 256 + threadIdx.x;
  if (i < 2 * SS) mf[i] = m[i] ? -1e30f : 0.f;
}

// generic f32 -> bf16 convert, 4 elems/thread (grid = n/1024 blocks of 256)
__global__ __launch_bounds__(256) void cvt_kernel(const float* __restrict__ src,
                                                  bf16* __restrict__ dst) {
  size_t i = ((size_t)blockIdx.x * 256 + threadIdx.x) * 4;
  float4 v = *(const float4*)(src + i);
  s4 p;
  p[0] = f2bs(v.x); p[1] = f2bs(v.y); p[2] = f2bs(v.z); p[3] = f2bs(v.w);
  *(s4*)(dst + i) = p;
}

// ---------------------------------------------------------------------------
// OLD direct-from-global proj (kept only for the small-ws f32 fallback path).
// Block: 256 thr = 4 waves; tile 128(m) x 64(n); wave: 32m x 64n.
template<int MODE, bool XB16, bool WB16>
__global__ __launch_bounds__(256) void proj_kernel(
    const void* __restrict__ Xv, const void* __restrict__ Wv,
    const float* __restrict__ bias, void* __restrict__ dstv,
    const float2* __restrict__ tab)
{
  const int w = threadIdx.x >> 6;
  const int lane = threadIdx.x & 63;
  const int l15 = lane & 15, quad = lane >> 4;
  const int tm = blockIdx.x * 128 + w * 32;
  const int tn = blockIdx.y * 64;

  const size_t aoff0 = (size_t)(tm + l15) * EE + quad * 8;
  const size_t aoff1 = aoff0 + (size_t)16 * EE;
  const size_t woff  = (size_t)(tn + l15) * EE + quad * 8;

  f32x4 zero4 = {0.f, 0.f, 0.f, 0.f};
  f32x4 acc[2][4];
#pragma unroll
  for (int mi = 0; mi < 2; ++mi)
#pragma unroll
    for (int ni = 0; ni < 4; ++ni) acc[mi][ni] = zero4;

  for (int k0 = 0; k0 < EE; k0 += 32) {
    bf16x8 a0, a1;
    if (XB16 || MODE == 3) {
      const bf16* Xb = (const bf16*)Xv;
      a0 = *(const bf16x8*)(Xb + aoff0 + k0);
      a1 = *(const bf16x8*)(Xb + aoff1 + k0);
    } else {
      const float* Xf = (const float*)Xv;
#pragma unroll
      for (int j = 0; j < 8; ++j) a0[j] = f2bs(Xf[aoff0 + k0 + j]);
#pragma unroll
      for (int j = 0; j < 8; ++j) a1[j] = f2bs(Xf[aoff1 + k0 + j]);
    }
#pragma unroll
    for (int ni = 0; ni < 4; ++ni) {
      bf16x8 bv;
      if (WB16) {
        const bf16* Wb = (const bf16*)Wv;
        bv = *(const bf16x8*)(Wb + woff + (size_t)ni * 16 * EE + k0);
      } else {
        const float* Wf = (const float*)Wv;
#pragma unroll
        for (int j = 0; j < 8; ++j) bv[j] = f2bs(Wf[woff + (size_t)ni * 16 * EE + k0 + j]);
      }
      acc[0][ni] = __builtin_amdgcn_mfma_f32_16x16x32_bf16(a0, bv, acc[0][ni], 0, 0, 0);
      acc[1][ni] = __builtin_amdgcn_mfma_f32_16x16x32_bf16(a1, bv, acc[1][ni], 0, 0, 0);
    }
  }

  float bz[4];
#pragma unroll
  for (int ni = 0; ni < 4; ++ni) bz[ni] = bias[tn + ni * 16 + l15];

#pragma unroll
  for (int mi = 0; mi < 2; ++mi) {
#pragma unroll
    for (int ni = 0; ni < 4; ++ni) {
      const int n = tn + ni * 16 + l15;
#pragma unroll
      for (int r = 0; r < 4; ++r) {
        const int m = tm + mi * 16 + quad * 4 + r;
        float v = acc[mi][ni][r] + bz[ni];
        if (MODE <= 1) {
          float other = __shfl_xor(v, 1, 64);        // pair element (n^1) is in lane^1
          int pos = m >> 1, b = m & 1, d = n & 63, h = n >> 6;
          float2 cs = tab[pos * 32 + (d >> 1)];
          float rv = (d & 1) ? (other * cs.y + v * cs.x) : (v * cs.x - other * cs.y);
          ((bf16*)dstv)[((size_t)(b * HH + h) * LL + pos) * HD + d] = __float2bfloat16(rv);
        } else if (MODE == 2) {
          int pos = m >> 1, b = m & 1, d = n & 63, h = n >> 6;
          ((bf16*)dstv)[((size_t)(b * HH + h) * HD + d) * SS + pos] = __float2bfloat16(v);
        } else {
          ((float*)dstv)[(size_t)m * EE + n] = v;
        }
      }
    }
  }
}

// ---------------------------------------------------------------------------
// NEW LDS-staged proj (m97 structure): global_load_lds width-16 staging,
// 2 barriers per K-step. Tile 128m x 64n, BK=32, 4 waves (wave: 32m x 64n).
// Grid (32,16) = 512 blocks = 2 blocks/CU.
// Bank-conflict fix per rule #21 (both-sides-or-neither): LDS dest stays
// LINEAR (gll requirement); the 16B chunk is swizzled on the GLOBAL SOURCE
// address (chunk c holds global chunk c ^ ((row>>1)&3)) and un-swizzled on the
// ds_read side with the same XOR -> 16 lanes spread over 8 bank groups = 2-way
// (free, m136) instead of 8-way (2.94x).
template<int MODE>
__global__ __launch_bounds__(256) void projs_kernel(
    const bf16* __restrict__ X, const bf16* __restrict__ W,
    const float* __restrict__ bias, void* __restrict__ dstv,
    const float2* __restrict__ tab)
{
  __shared__ __align__(16) bf16 As[128 * 32];   // 8 KB, row stride 32 (64 B)
  __shared__ __align__(16) bf16 Bs[64 * 32];    // 4 KB

  const int tid = threadIdx.x;
  const int w = tid >> 6;
  const int lane = tid & 63;
  const int l15 = lane & 15, quad = lane >> 4;
  const int tmb = blockIdx.x * 128;          // block m base
  const int tm  = tmb + w * 32;              // wave m base
  const int tn  = blockIdx.y * 64;

  // staging: thread t covers row t/4 (+64 for A round 1), 16B chunk t&3.
  // LDS byte dest = row*64 + chunk*16 = (wave-uniform) + lane*16. [verified]
  const int srow = tid >> 2;                 // 0..63
  const int schk = tid & 3;
  const int gc8  = (schk ^ ((srow >> 1) & 3)) * 8;   // swizzled source chunk (elems)
  const int swz  = (quad ^ ((l15 >> 1) & 3)) * 8;    // read-side chunk (elems)

  const bf16* gA0 = X + (size_t)(tmb + srow) * EE + gc8;        // ((64+srow)>>1)&3
  const bf16* gA1 = X + (size_t)(tmb + 64 + srow) * EE + gc8;   //  == (srow>>1)&3
  const bf16* gB  = W + (size_t)(tn + srow) * EE + gc8;
  bf16* lA0 = As + srow * 32 + schk * 8;
  bf16* lA1 = As + (64 + srow) * 32 + schk * 8;
  bf16* lB  = Bs + srow * 32 + schk * 8;

  f32x4 zero4 = {0.f, 0.f, 0.f, 0.f};
  f32x4 acc[2][4];
#pragma unroll
  for (int mi = 0; mi < 2; ++mi)
#pragma unroll
    for (int ni = 0; ni < 4; ++ni) acc[mi][ni] = zero4;

  for (int k0 = 0; k0 < EE; k0 += 32) {
    GLL16(gA0 + k0, lA0);
    GLL16(gA1 + k0, lA1);
    GLL16(gB + k0, lB);
    __syncthreads();   // compiler emits s_waitcnt vmcnt(0) before s_barrier -> LDS ready
    bf16x8 af0 = *(const bf16x8*)(As + (w * 32 + l15) * 32 + swz);
    bf16x8 af1 = *(const bf16x8*)(As + (w * 32 + 16 + l15) * 32 + swz);
#pragma unroll
    for (int ni = 0; ni < 4; ++ni) {
      bf16x8 bfr = *(const bf16x8*)(Bs + (ni * 16 + l15) * 32 + swz);
      acc[0][ni] = __builtin_amdgcn_mfma_f32_16x16x32_bf16(af0, bfr, acc[0][ni], 0, 0, 0);
      acc[1][ni] = __builtin_amdgcn_mfma_f32_16x16x32_bf16(af1, bfr, acc[1][ni], 0, 0, 0);
    }
    __syncthreads();   // all waves done reading before next overwrite
  }

  float bz[4];
#pragma unroll
  for (int ni = 0; ni < 4; ++ni) bz[ni] = bias[tn + ni * 16 + l15];

#pragma unroll
  for (int mi = 0; mi < 2; ++mi) {
#pragma unroll
    for (int ni = 0; ni < 4; ++ni) {
      const int n = tn + ni * 16 + l15;
#pragma unroll
      for (int r = 0; r < 4; ++r) {
        const int m = tm + mi * 16 + quad * 4 + r;
        float v = acc[mi][ni][r] + bz[ni];
        if (MODE <= 1) {
          float other = __shfl_xor(v, 1, 64);        // pair element (n^1) is in lane^1
          int pos = m >> 1, b = m & 1, d = n & 63, h = n >> 6;
          float2 cs = tab[pos * 32 + (d >> 1)];
          float rv = (d & 1) ? (other * cs.y + v * cs.x) : (v * cs.x - other * cs.y);
          ((bf16*)dstv)[((size_t)(b * HH + h) * LL + pos) * HD + d] = __float2bfloat16(rv);
        } else if (MODE == 2) {
          int pos = m >> 1, b = m & 1, d = n & 63, h = n >> 6;
          ((bf16*)dstv)[((size_t)(b * HH + h) * HD + d) * SS + pos] = __float2bfloat16(v);
        } else {
          ((float*)dstv)[(size_t)m * EE + n] = v;
        }
      }
    }
  }
}

// ---------------------------------------------------------------------------
// Flash attention, no-running-max variant. S^T = K.Q^T (operand swap) so
// softmaxed P lands in LDS in A-operand layout; V pre-transposed [b][h][d][s].
// NEW this round: 16 q-rows/wave (grid 1024 blocks -> 16 waves/CU, ~45% occ,
// vs previous 8/CU grid cap) + DOUBLE-BUFFERED P with ONE narrow compiler
// fence per 32-s tile. The fence (between P-writes and the P-frag read) is
// required: per-lane write set [l15][quad*4] and read set [l15][quad*8] are
// disjoint for a single thread, so without it the compiler may hoist the
// cross-lane read above the writes. V-frags are loaded BEFORE the fence so
// their latency hides under QK^T/exp; tile i+1 (other buffer) can overlap
// tile i's PV. Wave-private LDS slices -> no __syncthreads anywhere.
// XCD-swizzled grid: bh = id&31 so a head's 32 q-blocks share one XCD's L2
// (per-XCD working set = 4 heads x 512 KB = 2 MB < 4 MB L2).
__global__ __launch_bounds__(256, 4) void attn_kernel(
    const bf16* __restrict__ Qr, const bf16* __restrict__ Kr,
    const bf16* __restrict__ Vt, const float* __restrict__ maskf,
    bf16* __restrict__ ctx)
{
  __shared__ __align__(16) short Plds[4][2][16][40];  // [wave][buf][q][s, stride 40] = 10 KB
  const int w = threadIdx.x >> 6;
  const int lane = threadIdx.x & 63;
  const int l15 = lane & 15, quad = lane >> 4;
  const int id = blockIdx.x;
  const int bh = id & 31;             // XCD = bh % 8 (id%8 == bh%8 since 32|id-bh)
  const int qt = id >> 5;             // 0..31 (64 q per block, 16 per wave)
  const int b = bh >> 4, h = bh & 15;
  const int q0 = qt * 64 + w * 16;

  const bf16* Qbh = Qr + (size_t)bh * LL * HD;
  const bf16* Kbh = Kr + (size_t)bh * SS * HD;
  const bf16* Vbh = Vt + (size_t)bh * HD * SS;
  const float* mrow = maskf + b * SS;

  bf16x8 qf0, qf1;
  {
    const bf16* qp = Qbh + (size_t)(q0 + l15) * HD + quad * 8;
    qf0 = *(const bf16x8*)(qp);
    qf1 = *(const bf16x8*)(qp + 32);
  }

  f32x4 zero4 = {0.f, 0.f, 0.f, 0.f};
  f32x4 o[4];
#pragma unroll
  for (int t = 0; t < 4; ++t) o[t] = zero4;
  float ps = 0.f;

  // One 32-s tile against buffer PB. QK^T -> exp -> P-write -> V-loads ->
  // fence -> P-read -> PV.
#define ATTN_TILE(S0, PB) {                                                    \
    const bf16* kp0 = Kbh + (size_t)((S0) + l15) * HD + quad * 8;              \
    const bf16* kp1 = kp0 + (size_t)16 * HD;                                   \
    bf16x8 kf00 = *(const bf16x8*)(kp0);                                       \
    bf16x8 kf01 = *(const bf16x8*)(kp0 + 32);                                  \
    bf16x8 kf10 = *(const bf16x8*)(kp1);                                       \
    bf16x8 kf11 = *(const bf16x8*)(kp1 + 32);                                  \
    f32x4 mv0 = *(const f32x4*)(mrow + (S0) + quad * 4);                       \
    f32x4 mv1 = *(const f32x4*)(mrow + (S0) + 16 + quad * 4);                  \
    f32x4 sc0 = zero4, sc1 = zero4;                                            \
    sc0 = __builtin_amdgcn_mfma_f32_16x16x32_bf16(kf00, qf0, sc0, 0, 0, 0);    \
    sc0 = __builtin_amdgcn_mfma_f32_16x16x32_bf16(kf01, qf1, sc0, 0, 0, 0);    \
    sc1 = __builtin_amdgcn_mfma_f32_16x16x32_bf16(kf10, qf0, sc1, 0, 0, 0);    \
    sc1 = __builtin_amdgcn_mfma_f32_16x16x32_bf16(kf11, qf1, sc1, 0, 0, 0);    \
    s4 pk0, pk1;                                                               \
    _Pragma("unroll")                                                          \
    for (int r = 0; r < 4; ++r) {                                              \
      float p = __expf(sc0[r] * 0.125f + mv0[r]); ps += p; pk0[r] = f2bs(p);   \
    }                                                                          \
    _Pragma("unroll")                                                          \
    for (int r = 0; r < 4; ++r) {                                              \
      float p = __expf(sc1[r] * 0.125f + mv1[r]); ps += p; pk1[r] = f2bs(p);   \
    }                                                                          \
    *(s4*)&(PB)[l15][quad * 4] = pk0;                                          \
    *(s4*)&(PB)[l15][16 + quad * 4] = pk1;                                     \
    bf16x8 vf0 = *(const bf16x8*)(Vbh + (size_t)(l15) * SS + (S0) + quad * 8); \
    bf16x8 vf1 = *(const bf16x8*)(Vbh + (size_t)(16 + l15) * SS + (S0) + quad * 8); \
    bf16x8 vf2 = *(const bf16x8*)(Vbh + (size_t)(32 + l15) * SS + (S0) + quad * 8); \
    bf16x8 vf3 = *(const bf16x8*)(Vbh + (size_t)(48 + l15) * SS + (S0) + quad * 8); \
    asm volatile("" ::: "memory");  /* order: all lanes' P-writes before P-read */ \
    bf16x8 pf = *(const bf16x8*)&(PB)[l15][quad * 8];                          \
    o[0] = __builtin_amdgcn_mfma_f32_16x16x32_bf16(pf, vf0, o[0], 0, 0, 0);    \
    o[1] = __builtin_amdgcn_mfma_f32_16x16x32_bf16(pf, vf1, o[1], 0, 0, 0);    \
    o[2] = __builtin_amdgcn_mfma_f32_16x16x32_bf16(pf, vf2, o[2], 0, 0, 0);    \
    o[3] = __builtin_amdgcn_mfma_f32_16x16x32_bf16(pf, vf3, o[3], 0, 0, 0);    \
  }

  for (int s0 = 0; s0 < SS; s0 += 64) {
    ATTN_TILE(s0,      Plds[w][0]);
    ATTN_TILE(s0 + 32, Plds[w][1]);
  }
#undef ATTN_TILE

  // softmax denominator: lane holds partial for q = l15; sum across quads
  float lv = ps;
  lv += __shfl_xor(lv, 16, 64);
  lv += __shfl_xor(lv, 32, 64);

#pragma unroll
  for (int r = 0; r < 4; ++r) {
    float li = __shfl(lv, quad * 4 + r, 64);   // denom for q-row quad*4+r sits at lane l15==that
    float inv = 1.0f / li;
    int q = q0 + quad * 4 + r;
#pragma unroll
    for (int t = 0; t < 4; ++t) {
      float val = o[t][r] * inv;
      ctx[(size_t)(q * 2 + b) * EE + (size_t)h * 64 + t * 16 + l15] = __float2bfloat16(val);
    }
  }
}

extern "C" void kernel_launch(void* const* d_in, const int* in_sizes, int n_in,
                              void* d_out, int out_size, void* d_ws, size_t ws_size,
                              hipStream_t stream) {
  const float* query = (const float*)d_in[0];
  const float* key   = (const float*)d_in[1];
  const float* value = (const float*)d_in[2];
  const unsigned char* mask = (const unsigned char*)d_in[3];
  const float* Wq = (const float*)d_in[4];
  const float* bq = (const float*)d_in[5];
  const float* Wk = (const float*)d_in[6];
  const float* bk = (const float*)d_in[7];
  const float* Wv = (const float*)d_in[8];
  const float* bv = (const float*)d_in[9];
  const float* Wo = (const float*)d_in[10];
  const float* bo = (const float*)d_in[11];

  char* ws = (char*)d_ws;
  const bool big = ws_size >= ((size_t)41 << 20);

  // Layout A (small, <=33 MB): tab@0 | Qr@1M | Kr@9M | Vt@17M | ctx@25M
  // Layout B (big, 41 MB): tab@0 | Wb@1M (8 MB) | Xb/ctx@9M (8 MB) | Qr@17M | Kr@25M | Vt@33M
  float2* tab   = (float2*)ws;                          // 512 KB
  float*  maskf = (float*)(ws + (512 << 10));           // 16 KB (inside tab's MB)
  bf16* Wb = (bf16*)(ws + ((size_t)1 << 20));           // big only: 4 x 1M bf16
  bf16* Xb = (bf16*)(ws + ((size_t)9 << 20));           // big only; doubles as ctx
  size_t base = big ? ((size_t)17 << 20) : ((size_t)1 << 20);
  bf16* Qr  = (bf16*)(ws + base);                       // [b][h][l][d]
  bf16* Kr  = (bf16*)(ws + base + ((size_t)8 << 20));   // [b][h][s][d]
  bf16* Vt  = (bf16*)(ws + base + ((size_t)16 << 20));  // [b][h][d][s]
  bf16* ctx = big ? Xb : (bf16*)(ws + ((size_t)25 << 20));

  rope_table_kernel<<<(LL * 32) / 256, 256, 0, stream>>>(tab);
  maskf_kernel<<<16, 256, 0, stream>>>(mask, maskf);

  dim3 gp(MM / 128, EE / 64);
  if (big) {
    // weights: 4 x 1M elems -> Wb; inputs converted serially through Xb
    cvt_kernel<<<1024, 256, 0, stream>>>(Wq, Wb);
    cvt_kernel<<<1024, 256, 0, stream>>>(Wk, Wb + (size_t)EE * EE);
    cvt_kernel<<<1024, 256, 0, stream>>>(Wv, Wb + (size_t)2 * EE * EE);
    cvt_kernel<<<1024, 256, 0, stream>>>(Wo, Wb + (size_t)3 * EE * EE);
    cvt_kernel<<<4096, 256, 0, stream>>>(query, Xb);
    projs_kernel<0><<<gp, 256, 0, stream>>>(Xb, Wb, bq, Qr, tab);
    cvt_kernel<<<4096, 256, 0, stream>>>(key, Xb);
    projs_kernel<1><<<gp, 256, 0, stream>>>(Xb, Wb + (size_t)EE * EE, bk, Kr, tab);
    cvt_kernel<<<4096, 256, 0, stream>>>(value, Xb);
    projs_kernel<2><<<gp, 256, 0, stream>>>(Xb, Wb + (size_t)2 * EE * EE, bv, Vt, tab);
  } else {
    proj_kernel<0, false, false><<<gp, 256, 0, stream>>>(query, Wq, bq, Qr, tab);
    proj_kernel<1, false, false><<<gp, 256, 0, stream>>>(key,   Wk, bk, Kr, tab);
    proj_kernel<2, false, false><<<gp, 256, 0, stream>>>(value, Wv, bv, Vt, tab);
  }

  attn_kernel<<<(LL / 64) * 2 * HH, 256, 0, stream>>>(Qr, Kr, Vt, maskf, ctx);

  if (big) projs_kernel<3><<<gp, 256, 0, stream>>>(ctx, Wb + (size_t)3 * EE * EE, bo, d_out, tab);
  else     proj_kernel<3, true, false><<<gp, 256, 0, stream>>>(ctx, Wo, bo, d_out, tab);
}

// Round 2
// 270.660 us; speedup vs baseline: 1.6708x; 1.6708x over previous
//
#include <hip/hip_runtime.h>
#include <hip/hip_bf16.h>

typedef __hip_bfloat16 bf16;
typedef short bf16x8 __attribute__((ext_vector_type(8)));   // 8 bf16 = 4 VGPRs (MFMA frag)
typedef float f32x4 __attribute__((ext_vector_type(4)));
typedef short s4 __attribute__((ext_vector_type(4)));

#define LL 2048
#define SS 2048
#define EE 1024
#define HH 16
#define HD 64
#define MM (LL * 2)   // 4096 rows (l*B+b)

static __device__ __forceinline__ short f2bs(float f) {
  bf16 h = __float2bfloat16(f);
  short u;
  __builtin_memcpy(&u, &h, 2);
  return u;
}

// async global->LDS, 16B per lane. LDS dest must be wave-uniform base + lane*16.
#define GLL16(gp, lp) __builtin_amdgcn_global_load_lds(                        \
    (const __attribute__((address_space(1))) void*)(gp),                       \
    (__attribute__((address_space(3))) void*)(lp), 16, 0, 0)

// cos/sin table: tab[pos*32 + fi] = {cos(pos*invfreq[fi]), sin(...)}
__global__ __launch_bounds__(256) void rope_table_kernel(float2* __restrict__ tab) {
  int i = blockIdx.x * 256 + threadIdx.x;     // 2048*32 entries
  int pos = i >> 5, fi = i & 31;
  float freq = expf(-(float)fi * (9.210340371976184f / 32.0f));  // 10000^(-fi/32)
  float ang = (float)pos * freq;
  float s, c;
  sincosf(ang, &s, &c);
  tab[i] = make_float2(c, s);
}

// mask byte -> additive float bias (-1e30 masked, 0 else). B*S = 4096 entries.
__global__ void maskf_kernel(const unsigned char* __restrict__ m,
                             float* __restrict__ mf) {
  int i = blockIdx.x * 256 + threadIdx.x;
  if (i < 2 * SS) mf[i] = m[i] ? -1e30f : 0.f;
}

// generic f32 -> bf16 convert, 4 elems/thread (grid = n/1024 blocks of 256)
__global__ __launch_bounds__(256) void cvt_kernel(const float* __restrict__ src,
                                                  bf16* __restrict__ dst) {
  size_t i = ((size_t)blockIdx.x * 256 + threadIdx.x) * 4;
  float4 v = *(const float4*)(src + i);
  s4 p;
  p[0] = f2bs(v.x); p[1] = f2bs(v.y); p[2] = f2bs(v.z); p[3] = f2bs(v.w);
  *(s4*)(dst + i) = p;
}

// ---------------------------------------------------------------------------
// OLD direct-from-global proj (kept only for the small-ws f32 fallback path).
template<int MODE, bool XB16, bool WB16>
__global__ __launch_bounds__(256) void proj_kernel(
    const void* __restrict__ Xv, const void* __restrict__ Wv,
    const float* __restrict__ bias, void* __restrict__ dstv,
    const float2* __restrict__ tab)
{
  const int w = threadIdx.x >> 6;
  const int lane = threadIdx.x & 63;
  const int l15 = lane & 15, quad = lane >> 4;
  const int tm = blockIdx.x * 128 + w * 32;
  const int tn = blockIdx.y * 64;

  const size_t aoff0 = (size_t)(tm + l15) * EE + quad * 8;
  const size_t aoff1 = aoff0 + (size_t)16 * EE;
  const size_t woff  = (size_t)(tn + l15) * EE + quad * 8;

  f32x4 zero4 = {0.f, 0.f, 0.f, 0.f};
  f32x4 acc[2][4];
#pragma unroll
  for (int mi = 0; mi < 2; ++mi)
#pragma unroll
    for (int ni = 0; ni < 4; ++ni) acc[mi][ni] = zero4;

  for (int k0 = 0; k0 < EE; k0 += 32) {
    bf16x8 a0, a1;
    if (XB16 || MODE == 3) {
      const bf16* Xb = (const bf16*)Xv;
      a0 = *(const bf16x8*)(Xb + aoff0 + k0);
      a1 = *(const bf16x8*)(Xb + aoff1 + k0);
    } else {
      const float* Xf = (const float*)Xv;
#pragma unroll
      for (int j = 0; j < 8; ++j) a0[j] = f2bs(Xf[aoff0 + k0 + j]);
#pragma unroll
      for (int j = 0; j < 8; ++j) a1[j] = f2bs(Xf[aoff1 + k0 + j]);
    }
#pragma unroll
    for (int ni = 0; ni < 4; ++ni) {
      bf16x8 bv;
      if (WB16) {
        const bf16* Wb = (const bf16*)Wv;
        bv = *(const bf16x8*)(Wb + woff + (size_t)ni * 16 * EE + k0);
      } else {
        const float* Wf = (const float*)Wv;
#pragma unroll
        for (int j = 0; j < 8; ++j) bv[j] = f2bs(Wf[woff + (size_t)ni * 16 * EE + k0 + j]);
      }
      acc[0][ni] = __builtin_amdgcn_mfma_f32_16x16x32_bf16(a0, bv, acc[0][ni], 0, 0, 0);
      acc[1][ni] = __builtin_amdgcn_mfma_f32_16x16x32_bf16(a1, bv, acc[1][ni], 0, 0, 0);
    }
  }

  float bz[4];
#pragma unroll
  for (int ni = 0; ni < 4; ++ni) bz[ni] = bias[tn + ni * 16 + l15];

#pragma unroll
  for (int mi = 0; mi < 2; ++mi) {
#pragma unroll
    for (int ni = 0; ni < 4; ++ni) {
      const int n = tn + ni * 16 + l15;
#pragma unroll
      for (int r = 0; r < 4; ++r) {
        const int m = tm + mi * 16 + quad * 4 + r;
        float v = acc[mi][ni][r] + bz[ni];
        if (MODE <= 1) {
          float other = __shfl_xor(v, 1, 64);        // pair element (n^1) is in lane^1
          int pos = m >> 1, b = m & 1, d = n & 63, h = n >> 6;
          float2 cs = tab[pos * 32 + (d >> 1)];
          float rv = (d & 1) ? (other * cs.y + v * cs.x) : (v * cs.x - other * cs.y);
          ((bf16*)dstv)[((size_t)(b * HH + h) * LL + pos) * HD + d] = __float2bfloat16(rv);
        } else if (MODE == 2) {
          int pos = m >> 1, b = m & 1, d = n & 63, h = n >> 6;
          ((bf16*)dstv)[((size_t)(b * HH + h) * HD + d) * SS + pos] = __float2bfloat16(v);
        } else {
          ((float*)dstv)[(size_t)m * EE + n] = v;
        }
      }
    }
  }
}

// ---------------------------------------------------------------------------
// LDS-staged proj (m97 structure) — unchanged from round 1 (it worked).
template<int MODE>
__global__ __launch_bounds__(256) void projs_kernel(
    const bf16* __restrict__ X, const bf16* __restrict__ W,
    const float* __restrict__ bias, void* __restrict__ dstv,
    const float2* __restrict__ tab)
{
  __shared__ __align__(16) bf16 As[128 * 32];   // 8 KB, row stride 32 (64 B)
  __shared__ __align__(16) bf16 Bs[64 * 32];    // 4 KB

  const int tid = threadIdx.x;
  const int w = tid >> 6;
  const int lane = tid & 63;
  const int l15 = lane & 15, quad = lane >> 4;
  const int tmb = blockIdx.x * 128;          // block m base
  const int tm  = tmb + w * 32;              // wave m base
  const int tn  = blockIdx.y * 64;

  const int srow = tid >> 2;                 // 0..63
  const int schk = tid & 3;
  const int gc8  = (schk ^ ((srow >> 1) & 3)) * 8;   // swizzled source chunk (elems)
  const int swz  = (quad ^ ((l15 >> 1) & 3)) * 8;    // read-side chunk (elems)

  const bf16* gA0 = X + (size_t)(tmb + srow) * EE + gc8;
  const bf16* gA1 = X + (size_t)(tmb + 64 + srow) * EE + gc8;
  const bf16* gB  = W + (size_t)(tn + srow) * EE + gc8;
  bf16* lA0 = As + srow * 32 + schk * 8;
  bf16* lA1 = As + (64 + srow) * 32 + schk * 8;
  bf16* lB  = Bs + srow * 32 + schk * 8;

  f32x4 zero4 = {0.f, 0.f, 0.f, 0.f};
  f32x4 acc[2][4];
#pragma unroll
  for (int mi = 0; mi < 2; ++mi)
#pragma unroll
    for (int ni = 0; ni < 4; ++ni) acc[mi][ni] = zero4;

  for (int k0 = 0; k0 < EE; k0 += 32) {
    GLL16(gA0 + k0, lA0);
    GLL16(gA1 + k0, lA1);
    GLL16(gB + k0, lB);
    __syncthreads();   // vmcnt(0) drain before s_barrier -> LDS ready
    bf16x8 af0 = *(const bf16x8*)(As + (w * 32 + l15) * 32 + swz);
    bf16x8 af1 = *(const bf16x8*)(As + (w * 32 + 16 + l15) * 32 + swz);
#pragma unroll
    for (int ni = 0; ni < 4; ++ni) {
      bf16x8 bfr = *(const bf16x8*)(Bs + (ni * 16 + l15) * 32 + swz);
      acc[0][ni] = __builtin_amdgcn_mfma_f32_16x16x32_bf16(af0, bfr, acc[0][ni], 0, 0, 0);
      acc[1][ni] = __builtin_amdgcn_mfma_f32_16x16x32_bf16(af1, bfr, acc[1][ni], 0, 0, 0);
    }
    __syncthreads();   // all waves done reading before next overwrite
  }

  float bz[4];
#pragma unroll
  for (int ni = 0; ni < 4; ++ni) bz[ni] = bias[tn + ni * 16 + l15];

#pragma unroll
  for (int mi = 0; mi < 2; ++mi) {
#pragma unroll
    for (int ni = 0; ni < 4; ++ni) {
      const int n = tn + ni * 16 + l15;
#pragma unroll
      for (int r = 0; r < 4; ++r) {
        const int m = tm + mi * 16 + quad * 4 + r;
        float v = acc[mi][ni][r] + bz[ni];
        if (MODE <= 1) {
          float other = __shfl_xor(v, 1, 64);        // pair element (n^1) is in lane^1
          int pos = m >> 1, b = m & 1, d = n & 63, h = n >> 6;
          float2 cs = tab[pos * 32 + (d >> 1)];
          float rv = (d & 1) ? (other * cs.y + v * cs.x) : (v * cs.x - other * cs.y);
          ((bf16*)dstv)[((size_t)(b * HH + h) * LL + pos) * HD + d] = __float2bfloat16(rv);
        } else if (MODE == 2) {
          int pos = m >> 1, b = m & 1, d = n & 63, h = n >> 6;
          ((bf16*)dstv)[((size_t)(b * HH + h) * HD + d) * SS + pos] = __float2bfloat16(v);
        } else {
          ((float*)dstv)[(size_t)m * EE + n] = v;
        }
      }
    }
  }
}

// ---------------------------------------------------------------------------
// Flash attention, no-running-max variant, ROUND-2 structure:
// 32 q/wave restored (round-0 amortization — round-1 proved the kernel is
// vmem-THROUGHPUT bound at ~16B/cyc/CU, so traffic/output is what matters).
// K and V tiles (64 s) staged ONCE PER BLOCK into LDS via global_load_lds and
// shared by all 4 waves -> 4x less global traffic; per-wave reads move to the
// ~5x-faster ds_read path. Double-buffered tiles, ONE __syncthreads per 64-s
// tile (m97 pattern: barrier's vmcnt drain publishes next buffer + protects
// current). Bank-conflict fix per rule #21: LDS linear (gll requirement),
// chunk XOR'd with (row&7) on the GLOBAL SOURCE and identically on ds_read
// (m214's proven (row&7)<<4 pattern for [rows][128B] tiles; K rows = 64 bf16
// = 128B, V staged as [64d][64s] so V rows are 128B too).
// P stays in wave-private LDS slices with compiler fences (round-0-proven).
// XCD-swizzled grid: bh = id&31 -> a head's q-blocks share one XCD's L2.
__global__ __launch_bounds__(256) void attn_kernel(
    const bf16* __restrict__ Qr, const bf16* __restrict__ Kr,
    const bf16* __restrict__ Vt, const float* __restrict__ maskf,
    bf16* __restrict__ ctx)
{
  __shared__ __align__(16) bf16 Ks[2][64 * 64];       // 16 KB: [buf][s][d]
  __shared__ __align__(16) bf16 Vs[2][64 * 64];       // 16 KB: [buf][d][s]
  __shared__ __align__(16) short Plds[4][32][56];     // 14 KB: [wave][q][s str 56]

  const int w = threadIdx.x >> 6;
  const int lane = threadIdx.x & 63;
  const int l15 = lane & 15, quad = lane >> 4;
  const int id = blockIdx.x;
  const int bh = id & 31;             // XCD = bh % 8
  const int qt = id >> 5;             // 0..15
  const int b = bh >> 4, h = bh & 15;
  const int q0 = qt * 128 + w * 32;

  const bf16* Qbh = Qr + (size_t)bh * LL * HD;
  const bf16* Kbh = Kr + (size_t)bh * SS * HD;
  const bf16* Vbh = Vt + (size_t)bh * HD * SS;
  const float* mrow = maskf + b * SS;

  bf16x8 qf[2][2];
#pragma unroll
  for (int mi = 0; mi < 2; ++mi) {
    const bf16* qp = Qbh + (size_t)(q0 + mi * 16 + l15) * HD + quad * 8;
    qf[mi][0] = *(const bf16x8*)(qp);
    qf[mi][1] = *(const bf16x8*)(qp + 32);
  }

  // staging lane map: each wave stages 16 rows of K and 16 rows of V
  // (2 gll each; 8 rows x 8 chunks per gll). row&7 == lane>>3 for all instrs.
  const int srow = lane >> 3;                     // 0..7
  const int gswz = ((lane & 7) ^ srow) * 8;       // source chunk, elems
  // read-side swizzled chunk offsets (row&7 == l15&7 for all frag reads)
  const int kswz0 = ((quad    ) ^ (l15 & 7)) * 8;
  const int kswz1 = ((quad + 4) ^ (l15 & 7)) * 8;

#define STAGE(buf, S0) {                                                       \
    _Pragma("unroll")                                                          \
    for (int i = 0; i < 2; ++i) {                                              \
      const int rb = w * 16 + i * 8;                                           \
      GLL16(Kbh + (size_t)((S0) + rb + srow) * HD + gswz,                      \
            (bf16*)&Ks[buf][rb * 64] + lane * 8);                              \
      GLL16(Vbh + (size_t)(rb + srow) * SS + (S0) + gswz,                      \
            (bf16*)&Vs[buf][rb * 64] + lane * 8);                              \
    }                                                                          \
  }

  f32x4 zero4 = {0.f, 0.f, 0.f, 0.f};
  f32x4 o[2][4];
#pragma unroll
  for (int mi = 0; mi < 2; ++mi)
#pragma unroll
    for (int t = 0; t < 4; ++t) o[mi][t] = zero4;
  float ps0 = 0.f, ps1 = 0.f;

  STAGE(0, 0);
  __syncthreads();

  for (int t = 0; t < SS / 64; ++t) {
    const int s0 = t * 64;
    const int cur = t & 1;
    if (t + 1 < SS / 64) STAGE(cur ^ 1, s0 + 64);   // prefetch next 64-s tile

#pragma unroll
    for (int ss = 0; ss < 2; ++ss) {
      const bf16* Kb = &Ks[cur][ss * 32 * 64];
      bf16x8 kf00 = *(const bf16x8*)(Kb + (l15)      * 64 + kswz0);
      bf16x8 kf01 = *(const bf16x8*)(Kb + (l15)      * 64 + kswz1);
      bf16x8 kf10 = *(const bf16x8*)(Kb + (16 + l15) * 64 + kswz0);
      bf16x8 kf11 = *(const bf16x8*)(Kb + (16 + l15) * 64 + kswz1);
      bf16x8 vf[4];
#pragma unroll
      for (int tt = 0; tt < 4; ++tt)
        vf[tt] = *(const bf16x8*)(&Vs[cur][0] + (tt * 16 + l15) * 64 +
                                  (((ss * 4 + quad) ^ (l15 & 7)) * 8));
      f32x4 mv0 = *(const f32x4*)(mrow + s0 + ss * 32 + quad * 4);
      f32x4 mv1 = *(const f32x4*)(mrow + s0 + ss * 32 + 16 + quad * 4);

#pragma unroll
      for (int mi = 0; mi < 2; ++mi) {
        f32x4 sc0 = zero4, sc1 = zero4;
        sc0 = __builtin_amdgcn_mfma_f32_16x16x32_bf16(kf00, qf[mi][0], sc0, 0, 0, 0);
        sc0 = __builtin_amdgcn_mfma_f32_16x16x32_bf16(kf01, qf[mi][1], sc0, 0, 0, 0);
        sc1 = __builtin_amdgcn_mfma_f32_16x16x32_bf16(kf10, qf[mi][0], sc1, 0, 0, 0);
        sc1 = __builtin_amdgcn_mfma_f32_16x16x32_bf16(kf11, qf[mi][1], sc1, 0, 0, 0);
        // S^T tile: C row = s_local = quad*4+r, C col = q_local = l15
        s4 pk0, pk1;
#pragma unroll
        for (int r = 0; r < 4; ++r) {
          float p = __expf(sc0[r] * 0.125f + mv0[r]);
          if (mi == 0) ps0 += p; else ps1 += p;
          pk0[r] = f2bs(p);
        }
#pragma unroll
        for (int r = 0; r < 4; ++r) {
          float p = __expf(sc1[r] * 0.125f + mv1[r]);
          if (mi == 0) ps0 += p; else ps1 += p;
          pk1[r] = f2bs(p);
        }
        *(s4*)&Plds[w][mi * 16 + l15][quad * 4] = pk0;
        *(s4*)&Plds[w][mi * 16 + l15][16 + quad * 4] = pk1;
      }
      asm volatile("" ::: "memory");   // all P-writes before cross-lane P-read
      bf16x8 pf0 = *(const bf16x8*)&Plds[w][l15][quad * 8];
      bf16x8 pf1 = *(const bf16x8*)&Plds[w][16 + l15][quad * 8];
#pragma unroll
      for (int tt = 0; tt < 4; ++tt) {
        o[0][tt] = __builtin_amdgcn_mfma_f32_16x16x32_bf16(pf0, vf[tt], o[0][tt], 0, 0, 0);
        o[1][tt] = __builtin_amdgcn_mfma_f32_16x16x32_bf16(pf1, vf[tt], o[1][tt], 0, 0, 0);
      }
      asm volatile("" ::: "memory");   // P-reads done before next subtile overwrites
    }
    __syncthreads();   // drains gll (next buf ready) + all waves done with cur
  }
#undef STAGE

  // softmax denominator: lane partials -> sum across quads (same q column l15)
  float lv0 = ps0; lv0 += __shfl_xor(lv0, 16, 64); lv0 += __shfl_xor(lv0, 32, 64);
  float lv1 = ps1; lv1 += __shfl_xor(lv1, 16, 64); lv1 += __shfl_xor(lv1, 32, 64);

#pragma unroll
  for (int mi = 0; mi < 2; ++mi) {
#pragma unroll
    for (int r = 0; r < 4; ++r) {
      float lv = (mi == 0) ? lv0 : lv1;
      float li = __shfl(lv, quad * 4 + r, 64);   // denom for q-row quad*4+r
      float inv = 1.0f / li;
      int q = q0 + mi * 16 + quad * 4 + r;
#pragma unroll
      for (int t = 0; t < 4; ++t) {
        float val = o[mi][t][r] * inv;
        ctx[(size_t)(q * 2 + b) * EE + (size_t)h * 64 + t * 16 + l15] = __float2bfloat16(val);
      }
    }
  }
}

extern "C" void kernel_launch(void* const* d_in, const int* in_sizes, int n_in,
                              void* d_out, int out_size, void* d_ws, size_t ws_size,
                              hipStream_t stream) {
  const float* query = (const float*)d_in[0];
  const float* key   = (const float*)d_in[1];
  const float* value = (const float*)d_in[2];
  const unsigned char* mask = (const unsigned char*)d_in[3];
  const float* Wq = (const float*)d_in[4];
  const float* bq = (const float*)d_in[5];
  const float* Wk = (const float*)d_in[6];
  const float* bk = (const float*)d_in[7];
  const float* Wv = (const float*)d_in[8];
  const float* bv = (const float*)d_in[9];
  const float* Wo = (const float*)d_in[10];
  const float* bo = (const float*)d_in[11];

  char* ws = (char*)d_ws;
  const bool big = ws_size >= ((size_t)41 << 20);

  // Layout A (small, <=33 MB): tab@0 | Qr@1M | Kr@9M | Vt@17M | ctx@25M
  // Layout B (big, 41 MB): tab@0 | Wb@1M (8 MB) | Xb/ctx@9M (8 MB) | Qr@17M | Kr@25M | Vt@33M
  float2* tab   = (float2*)ws;                          // 512 KB
  float*  maskf = (float*)(ws + (512 << 10));           // 16 KB (inside tab's MB)
  bf16* Wb = (bf16*)(ws + ((size_t)1 << 20));           // big only: 4 x 1M bf16
  bf16* Xb = (bf16*)(ws + ((size_t)9 << 20));           // big only; doubles as ctx
  size_t base = big ? ((size_t)17 << 20) : ((size_t)1 << 20);
  bf16* Qr  = (bf16*)(ws + base);                       // [b][h][l][d]
  bf16* Kr  = (bf16*)(ws + base + ((size_t)8 << 20));   // [b][h][s][d]
  bf16* Vt  = (bf16*)(ws + base + ((size_t)16 << 20));  // [b][h][d][s]
  bf16* ctx = big ? Xb : (bf16*)(ws + ((size_t)25 << 20));

  rope_table_kernel<<<(LL * 32) / 256, 256, 0, stream>>>(tab);
  maskf_kernel<<<16, 256, 0, stream>>>(mask, maskf);

  dim3 gp(MM / 128, EE / 64);
  if (big) {
    cvt_kernel<<<1024, 256, 0, stream>>>(Wq, Wb);
    cvt_kernel<<<1024, 256, 0, stream>>>(Wk, Wb + (size_t)EE * EE);
    cvt_kernel<<<1024, 256, 0, stream>>>(Wv, Wb + (size_t)2 * EE * EE);
    cvt_kernel<<<1024, 256, 0, stream>>>(Wo, Wb + (size_t)3 * EE * EE);
    cvt_kernel<<<4096, 256, 0, stream>>>(query, Xb);
    projs_kernel<0><<<gp, 256, 0, stream>>>(Xb, Wb, bq, Qr, tab);
    cvt_kernel<<<4096, 256, 0, stream>>>(key, Xb);
    projs_kernel<1><<<gp, 256, 0, stream>>>(Xb, Wb + (size_t)EE * EE, bk, Kr, tab);
    cvt_kernel<<<4096, 256, 0, stream>>>(value, Xb);
    projs_kernel<2><<<gp, 256, 0, stream>>>(Xb, Wb + (size_t)2 * EE * EE, bv, Vt, tab);
  } else {
    proj_kernel<0, false, false><<<gp, 256, 0, stream>>>(query, Wq, bq, Qr, tab);
    proj_kernel<1, false, false><<<gp, 256, 0, stream>>>(key,   Wk, bk, Kr, tab);
    proj_kernel<2, false, false><<<gp, 256, 0, stream>>>(value, Wv, bv, Vt, tab);
  }

  attn_kernel<<<(LL / 128) * 2 * HH, 256, 0, stream>>>(Qr, Kr, Vt, maskf, ctx);

  if (big) projs_kernel<3><<<gp, 256, 0, stream>>>(ctx, Wb + (size_t)3 * EE * EE, bo, d_out, tab);
  else     proj_kernel<3, true, false><<<gp, 256, 0, stream>>>(ctx, Wo, bo, d_out, tab);
}

// Round 3
// 265.907 us; speedup vs baseline: 1.7006x; 1.0179x over previous
//
#include <hip/hip_runtime.h>
#include <hip/hip_bf16.h>

typedef __hip_bfloat16 bf16;
typedef short bf16x8 __attribute__((ext_vector_type(8)));   // 8 bf16 = 4 VGPRs (MFMA frag)
typedef float f32x4 __attribute__((ext_vector_type(4)));
typedef short s4 __attribute__((ext_vector_type(4)));

#define LL 2048
#define SS 2048
#define EE 1024
#define HH 16
#define HD 64
#define MM (LL * 2)   // 4096 rows (l*B+b)

static __device__ __forceinline__ short f2bs(float f) {
  bf16 h = __float2bfloat16(f);
  short u;
  __builtin_memcpy(&u, &h, 2);
  return u;
}

// async global->LDS, 16B per lane. LDS dest must be wave-uniform base + lane*16.
#define GLL16(gp, lp) __builtin_amdgcn_global_load_lds(                        \
    (const __attribute__((address_space(1))) void*)(gp),                       \
    (__attribute__((address_space(3))) void*)(lp), 16, 0, 0)

// cos/sin table (blocks 0..255) + mask->float bias (blocks 256..271).
__global__ __launch_bounds__(256) void tables_kernel(
    float2* __restrict__ tab, const unsigned char* __restrict__ m,
    float* __restrict__ mf) {
  if (blockIdx.x < 256) {
    int i = blockIdx.x * 256 + threadIdx.x;   // 2048*32 entries
    int pos = i >> 5, fi = i & 31;
    float freq = expf(-(float)fi * (9.210340371976184f / 32.0f));  // 10000^(-fi/32)
    float ang = (float)pos * freq;
    float s, c;
    sincosf(ang, &s, &c);
    tab[i] = make_float2(c, s);
  } else {
    int i = (blockIdx.x - 256) * 256 + threadIdx.x;
    if (i < 2 * SS) mf[i] = m[i] ? -1e30f : 0.f;
  }
}

// generic f32 -> bf16 convert, 4 elems/thread (grid = n/1024 blocks of 256)
__global__ __launch_bounds__(256) void cvt_kernel(const float* __restrict__ src,
                                                  bf16* __restrict__ dst) {
  size_t i = ((size_t)blockIdx.x * 256 + threadIdx.x) * 4;
  float4 v = *(const float4*)(src + i);
  s4 p;
  p[0] = f2bs(v.x); p[1] = f2bs(v.y); p[2] = f2bs(v.z); p[3] = f2bs(v.w);
  *(s4*)(dst + i) = p;
}

// 4 weight matrices (1M elems each) in one launch: grid 4096, sel = blk>>10.
__global__ __launch_bounds__(256) void cvt4_kernel(
    const float* __restrict__ s0, const float* __restrict__ s1,
    const float* __restrict__ s2, const float* __restrict__ s3,
    bf16* __restrict__ dst) {
  int sel = blockIdx.x >> 10;
  const float* src = (sel == 0) ? s0 : (sel == 1) ? s1 : (sel == 2) ? s2 : s3;
  size_t loc = ((size_t)(blockIdx.x & 1023) * 256 + threadIdx.x) * 4;
  float4 v = *(const float4*)(src + loc);
  s4 p;
  p[0] = f2bs(v.x); p[1] = f2bs(v.y); p[2] = f2bs(v.z); p[3] = f2bs(v.w);
  *(s4*)(dst + (size_t)sel * EE * EE + loc) = p;
}

// ---------------------------------------------------------------------------
// OLD direct-from-global proj (kept only for the small-ws f32 fallback path).
template<int MODE, bool XB16, bool WB16>
__global__ __launch_bounds__(256) void proj_kernel(
    const void* __restrict__ Xv, const void* __restrict__ Wv,
    const float* __restrict__ bias, void* __restrict__ dstv,
    const float2* __restrict__ tab)
{
  const int w = threadIdx.x >> 6;
  const int lane = threadIdx.x & 63;
  const int l15 = lane & 15, quad = lane >> 4;
  const int tm = blockIdx.x * 128 + w * 32;
  const int tn = blockIdx.y * 64;

  const size_t aoff0 = (size_t)(tm + l15) * EE + quad * 8;
  const size_t aoff1 = aoff0 + (size_t)16 * EE;
  const size_t woff  = (size_t)(tn + l15) * EE + quad * 8;

  f32x4 zero4 = {0.f, 0.f, 0.f, 0.f};
  f32x4 acc[2][4];
#pragma unroll
  for (int mi = 0; mi < 2; ++mi)
#pragma unroll
    for (int ni = 0; ni < 4; ++ni) acc[mi][ni] = zero4;

  for (int k0 = 0; k0 < EE; k0 += 32) {
    bf16x8 a0, a1;
    if (XB16 || MODE == 3) {
      const bf16* Xb = (const bf16*)Xv;
      a0 = *(const bf16x8*)(Xb + aoff0 + k0);
      a1 = *(const bf16x8*)(Xb + aoff1 + k0);
    } else {
      const float* Xf = (const float*)Xv;
#pragma unroll
      for (int j = 0; j < 8; ++j) a0[j] = f2bs(Xf[aoff0 + k0 + j]);
#pragma unroll
      for (int j = 0; j < 8; ++j) a1[j] = f2bs(Xf[aoff1 + k0 + j]);
    }
#pragma unroll
    for (int ni = 0; ni < 4; ++ni) {
      bf16x8 bv;
      if (WB16) {
        const bf16* Wb = (const bf16*)Wv;
        bv = *(const bf16x8*)(Wb + woff + (size_t)ni * 16 * EE + k0);
      } else {
        const float* Wf = (const float*)Wv;
#pragma unroll
        for (int j = 0; j < 8; ++j) bv[j] = f2bs(Wf[woff + (size_t)ni * 16 * EE + k0 + j]);
      }
      acc[0][ni] = __builtin_amdgcn_mfma_f32_16x16x32_bf16(a0, bv, acc[0][ni], 0, 0, 0);
      acc[1][ni] = __builtin_amdgcn_mfma_f32_16x16x32_bf16(a1, bv, acc[1][ni], 0, 0, 0);
    }
  }

  float bz[4];
#pragma unroll
  for (int ni = 0; ni < 4; ++ni) bz[ni] = bias[tn + ni * 16 + l15];

#pragma unroll
  for (int mi = 0; mi < 2; ++mi) {
#pragma unroll
    for (int ni = 0; ni < 4; ++ni) {
      const int n = tn + ni * 16 + l15;
#pragma unroll
      for (int r = 0; r < 4; ++r) {
        const int m = tm + mi * 16 + quad * 4 + r;
        float v = acc[mi][ni][r] + bz[ni];
        if (MODE <= 1) {
          float other = __shfl_xor(v, 1, 64);        // pair element (n^1) is in lane^1
          int pos = m >> 1, b = m & 1, d = n & 63, h = n >> 6;
          float2 cs = tab[pos * 32 + (d >> 1)];
          float rv = (d & 1) ? (other * cs.y + v * cs.x) : (v * cs.x - other * cs.y);
          ((bf16*)dstv)[((size_t)(b * HH + h) * LL + pos) * HD + d] = __float2bfloat16(rv);
        } else if (MODE == 2) {
          int pos = m >> 1, b = m & 1, d = n & 63, h = n >> 6;
          ((bf16*)dstv)[((size_t)(b * HH + h) * HD + d) * SS + pos] = __float2bfloat16(v);
        } else {
          ((float*)dstv)[(size_t)m * EE + n] = v;
        }
      }
    }
  }
}

// ---------------------------------------------------------------------------
// ROUND-3 proj: double-buffered LDS prefetch (the structure that fixed attn).
// Tile 128m x 64n, BK=64, one __syncthreads per K-step: issue 6 gll for tile
// t+1 -> compute 16 MFMA + 12 ds_read_b128 on tile t -> barrier (vmcnt drain
// lands AFTER a full compute phase => load latency hidden, vs round-2's
// synchronous 2-barrier loop that exposed it every 8 MFMAs).
// Bank-conflict fix per rule #21: LDS linear (gll requirement); 16B chunk
// XOR-swizzled with (row&7) on the GLOBAL SOURCE and identically on ds_read
// (attn-proven (row&7)<<4 pattern; A and B rows are both 128 B).
// LDS 48 KB -> 2 blocks/CU; grid (32,16) = 512 = 2/CU.
template<int MODE>
__global__ __launch_bounds__(256) void projs_kernel(
    const bf16* __restrict__ X, const bf16* __restrict__ W,
    const float* __restrict__ bias, void* __restrict__ dstv,
    const float2* __restrict__ tab)
{
  __shared__ __align__(16) bf16 As[2][128 * 64];   // 32 KB, row = 64 elems = 128 B
  __shared__ __align__(16) bf16 Bs[2][64 * 64];    // 16 KB

  const int tid = threadIdx.x;
  const int w = tid >> 6;
  const int lane = tid & 63;
  const int l15 = lane & 15, quad = lane >> 4;
  const int tmb = blockIdx.x * 128;
  const int tm  = tmb + w * 32;
  const int tn  = blockIdx.y * 64;

  // staging lane map per gll: 8 rows x 8 chunks; row = lane>>3, chunk = lane&7.
  // LDS dest = rowbase*128B + lane*16B (linear). Global chunk = chunk ^ (row&7).
  const int srow = lane >> 3;                 // 0..7 == row&7 for every gll
  const int sgc  = ((lane & 7) ^ srow) * 8;   // swizzled source chunk (elems)

  // A: 128 rows = 16 wave-instrs = 4/wave (8 rows each); B: 64 rows = 2/wave.
#define PSTAGE(buf, K0) {                                                      \
    _Pragma("unroll")                                                          \
    for (int i = 0; i < 4; ++i) {                                              \
      const int rb = w * 32 + i * 8;                                           \
      GLL16(X + (size_t)(tmb + rb + srow) * EE + (K0) + sgc,                   \
            (bf16*)&As[buf][rb * 64] + lane * 8);                              \
    }                                                                          \
    _Pragma("unroll")                                                          \
    for (int i = 0; i < 2; ++i) {                                              \
      const int rb = w * 16 + i * 8;                                           \
      GLL16(W + (size_t)(tn + rb + srow) * EE + (K0) + sgc,                    \
            (bf16*)&Bs[buf][rb * 64] + lane * 8);                              \
    }                                                                          \
  }

  f32x4 zero4 = {0.f, 0.f, 0.f, 0.f};
  f32x4 acc[2][4];
#pragma unroll
  for (int mi = 0; mi < 2; ++mi)
#pragma unroll
    for (int ni = 0; ni < 4; ++ni) acc[mi][ni] = zero4;

  PSTAGE(0, 0);
  __syncthreads();

  for (int t = 0; t < EE / 64; ++t) {
    const int cur = t & 1;
    if (t + 1 < EE / 64) PSTAGE(cur ^ 1, (t + 1) * 64);
#pragma unroll
    for (int ks = 0; ks < 2; ++ks) {
      const int rsw = ((ks * 4 + quad) ^ (l15 & 7)) * 8;   // read-side swizzle
      bf16x8 a0 = *(const bf16x8*)(&As[cur][0] + (w * 32 + l15) * 64 + rsw);
      bf16x8 a1 = *(const bf16x8*)(&As[cur][0] + (w * 32 + 16 + l15) * 64 + rsw);
#pragma unroll
      for (int ni = 0; ni < 4; ++ni) {
        bf16x8 bfr = *(const bf16x8*)(&Bs[cur][0] + (ni * 16 + l15) * 64 + rsw);
        acc[0][ni] = __builtin_amdgcn_mfma_f32_16x16x32_bf16(a0, bfr, acc[0][ni], 0, 0, 0);
        acc[1][ni] = __builtin_amdgcn_mfma_f32_16x16x32_bf16(a1, bfr, acc[1][ni], 0, 0, 0);
      }
    }
    __syncthreads();   // drains gll (next buf ready) + all waves done with cur
  }
#undef PSTAGE

  float bz[4];
#pragma unroll
  for (int ni = 0; ni < 4; ++ni) bz[ni] = bias[tn + ni * 16 + l15];

#pragma unroll
  for (int mi = 0; mi < 2; ++mi) {
#pragma unroll
    for (int ni = 0; ni < 4; ++ni) {
      const int n = tn + ni * 16 + l15;
#pragma unroll
      for (int r = 0; r < 4; ++r) {
        const int m = tm + mi * 16 + quad * 4 + r;
        float v = acc[mi][ni][r] + bz[ni];
        if (MODE <= 1) {
          float other = __shfl_xor(v, 1, 64);        // pair element (n^1) is in lane^1
          int pos = m >> 1, b = m & 1, d = n & 63, h = n >> 6;
          float2 cs = tab[pos * 32 + (d >> 1)];
          float rv = (d & 1) ? (other * cs.y + v * cs.x) : (v * cs.x - other * cs.y);
          ((bf16*)dstv)[((size_t)(b * HH + h) * LL + pos) * HD + d] = __float2bfloat16(rv);
        } else if (MODE == 2) {
          int pos = m >> 1, b = m & 1, d = n & 63, h = n >> 6;
          ((bf16*)dstv)[((size_t)(b * HH + h) * HD + d) * SS + pos] = __float2bfloat16(v);
        } else {
          ((float*)dstv)[(size_t)m * EE + n] = v;
        }
      }
    }
  }
}

// ---------------------------------------------------------------------------
// Flash attention — BYTE-IDENTICAL to round 2 (67.5 µs, proven).
__global__ __launch_bounds__(256) void attn_kernel(
    const bf16* __restrict__ Qr, const bf16* __restrict__ Kr,
    const bf16* __restrict__ Vt, const float* __restrict__ maskf,
    bf16* __restrict__ ctx)
{
  __shared__ __align__(16) bf16 Ks[2][64 * 64];       // 16 KB: [buf][s][d]
  __shared__ __align__(16) bf16 Vs[2][64 * 64];       // 16 KB: [buf][d][s]
  __shared__ __align__(16) short Plds[4][32][56];     // 14 KB: [wave][q][s str 56]

  const int w = threadIdx.x >> 6;
  const int lane = threadIdx.x & 63;
  const int l15 = lane & 15, quad = lane >> 4;
  const int id = blockIdx.x;
  const int bh = id & 31;             // XCD = bh % 8
  const int qt = id >> 5;             // 0..15
  const int b = bh >> 4, h = bh & 15;
  const int q0 = qt * 128 + w * 32;

  const bf16* Qbh = Qr + (size_t)bh * LL * HD;
  const bf16* Kbh = Kr + (size_t)bh * SS * HD;
  const bf16* Vbh = Vt + (size_t)bh * HD * SS;
  const float* mrow = maskf + b * SS;

  bf16x8 qf[2][2];
#pragma unroll
  for (int mi = 0; mi < 2; ++mi) {
    const bf16* qp = Qbh + (size_t)(q0 + mi * 16 + l15) * HD + quad * 8;
    qf[mi][0] = *(const bf16x8*)(qp);
    qf[mi][1] = *(const bf16x8*)(qp + 32);
  }

  const int srow = lane >> 3;                     // 0..7
  const int gswz = ((lane & 7) ^ srow) * 8;       // source chunk, elems
  const int kswz0 = ((quad    ) ^ (l15 & 7)) * 8;
  const int kswz1 = ((quad + 4) ^ (l15 & 7)) * 8;

#define STAGE(buf, S0) {                                                       \
    _Pragma("unroll")                                                          \
    for (int i = 0; i < 2; ++i) {                                              \
      const int rb = w * 16 + i * 8;                                           \
      GLL16(Kbh + (size_t)((S0) + rb + srow) * HD + gswz,                      \
            (bf16*)&Ks[buf][rb * 64] + lane * 8);                              \
      GLL16(Vbh + (size_t)(rb + srow) * SS + (S0) + gswz,                      \
            (bf16*)&Vs[buf][rb * 64] + lane * 8);                              \
    }                                                                          \
  }

  f32x4 zero4 = {0.f, 0.f, 0.f, 0.f};
  f32x4 o[2][4];
#pragma unroll
  for (int mi = 0; mi < 2; ++mi)
#pragma unroll
    for (int t = 0; t < 4; ++t) o[mi][t] = zero4;
  float ps0 = 0.f, ps1 = 0.f;

  STAGE(0, 0);
  __syncthreads();

  for (int t = 0; t < SS / 64; ++t) {
    const int s0 = t * 64;
    const int cur = t & 1;
    if (t + 1 < SS / 64) STAGE(cur ^ 1, s0 + 64);   // prefetch next 64-s tile

#pragma unroll
    for (int ss = 0; ss < 2; ++ss) {
      const bf16* Kb = &Ks[cur][ss * 32 * 64];
      bf16x8 kf00 = *(const bf16x8*)(Kb + (l15)      * 64 + kswz0);
      bf16x8 kf01 = *(const bf16x8*)(Kb + (l15)      * 64 + kswz1);
      bf16x8 kf10 = *(const bf16x8*)(Kb + (16 + l15) * 64 + kswz0);
      bf16x8 kf11 = *(const bf16x8*)(Kb + (16 + l15) * 64 + kswz1);
      bf16x8 vf[4];
#pragma unroll
      for (int tt = 0; tt < 4; ++tt)
        vf[tt] = *(const bf16x8*)(&Vs[cur][0] + (tt * 16 + l15) * 64 +
                                  (((ss * 4 + quad) ^ (l15 & 7)) * 8));
      f32x4 mv0 = *(const f32x4*)(mrow + s0 + ss * 32 + quad * 4);
      f32x4 mv1 = *(const f32x4*)(mrow + s0 + ss * 32 + 16 + quad * 4);

#pragma unroll
      for (int mi = 0; mi < 2; ++mi) {
        f32x4 sc0 = zero4, sc1 = zero4;
        sc0 = __builtin_amdgcn_mfma_f32_16x16x32_bf16(kf00, qf[mi][0], sc0, 0, 0, 0);
        sc0 = __builtin_amdgcn_mfma_f32_16x16x32_bf16(kf01, qf[mi][1], sc0, 0, 0, 0);
        sc1 = __builtin_amdgcn_mfma_f32_16x16x32_bf16(kf10, qf[mi][0], sc1, 0, 0, 0);
        sc1 = __builtin_amdgcn_mfma_f32_16x16x32_bf16(kf11, qf[mi][1], sc1, 0, 0, 0);
        s4 pk0, pk1;
#pragma unroll
        for (int r = 0; r < 4; ++r) {
          float p = __expf(sc0[r] * 0.125f + mv0[r]);
          if (mi == 0) ps0 += p; else ps1 += p;
          pk0[r] = f2bs(p);
        }
#pragma unroll
        for (int r = 0; r < 4; ++r) {
          float p = __expf(sc1[r] * 0.125f + mv1[r]);
          if (mi == 0) ps0 += p; else ps1 += p;
          pk1[r] = f2bs(p);
        }
        *(s4*)&Plds[w][mi * 16 + l15][quad * 4] = pk0;
        *(s4*)&Plds[w][mi * 16 + l15][16 + quad * 4] = pk1;
      }
      asm volatile("" ::: "memory");   // all P-writes before cross-lane P-read
      bf16x8 pf0 = *(const bf16x8*)&Plds[w][l15][quad * 8];
      bf16x8 pf1 = *(const bf16x8*)&Plds[w][16 + l15][quad * 8];
#pragma unroll
      for (int tt = 0; tt < 4; ++tt) {
        o[0][tt] = __builtin_amdgcn_mfma_f32_16x16x32_bf16(pf0, vf[tt], o[0][tt], 0, 0, 0);
        o[1][tt] = __builtin_amdgcn_mfma_f32_16x16x32_bf16(pf1, vf[tt], o[1][tt], 0, 0, 0);
      }
      asm volatile("" ::: "memory");   // P-reads done before next subtile overwrites
    }
    __syncthreads();   // drains gll (next buf ready) + all waves done with cur
  }
#undef STAGE

  float lv0 = ps0; lv0 += __shfl_xor(lv0, 16, 64); lv0 += __shfl_xor(lv0, 32, 64);
  float lv1 = ps1; lv1 += __shfl_xor(lv1, 16, 64); lv1 += __shfl_xor(lv1, 32, 64);

#pragma unroll
  for (int mi = 0; mi < 2; ++mi) {
#pragma unroll
    for (int r = 0; r < 4; ++r) {
      float lv = (mi == 0) ? lv0 : lv1;
      float li = __shfl(lv, quad * 4 + r, 64);   // denom for q-row quad*4+r
      float inv = 1.0f / li;
      int q = q0 + mi * 16 + quad * 4 + r;
#pragma unroll
      for (int t = 0; t < 4; ++t) {
        float val = o[mi][t][r] * inv;
        ctx[(size_t)(q * 2 + b) * EE + (size_t)h * 64 + t * 16 + l15] = __float2bfloat16(val);
      }
    }
  }
}

extern "C" void kernel_launch(void* const* d_in, const int* in_sizes, int n_in,
                              void* d_out, int out_size, void* d_ws, size_t ws_size,
                              hipStream_t stream) {
  const float* query = (const float*)d_in[0];
  const float* key   = (const float*)d_in[1];
  const float* value = (const float*)d_in[2];
  const unsigned char* mask = (const unsigned char*)d_in[3];
  const float* Wq = (const float*)d_in[4];
  const float* bq = (const float*)d_in[5];
  const float* Wk = (const float*)d_in[6];
  const float* bk = (const float*)d_in[7];
  const float* Wv = (const float*)d_in[8];
  const float* bv = (const float*)d_in[9];
  const float* Wo = (const float*)d_in[10];
  const float* bo = (const float*)d_in[11];

  char* ws = (char*)d_ws;
  const bool big = ws_size >= ((size_t)41 << 20);

  // Layout A (small, <=33 MB): tab@0 | Qr@1M | Kr@9M | Vt@17M | ctx@25M
  // Layout B (big, 41 MB): tab@0 | Wb@1M (8 MB) | Xb/ctx@9M (8 MB) | Qr@17M | Kr@25M | Vt@33M
  float2* tab   = (float2*)ws;                          // 512 KB
  float*  maskf = (float*)(ws + (512 << 10));           // 16 KB (inside tab's MB)
  bf16* Wb = (bf16*)(ws + ((size_t)1 << 20));           // big only: 4 x 1M bf16
  bf16* Xb = (bf16*)(ws + ((size_t)9 << 20));           // big only; doubles as ctx
  size_t base = big ? ((size_t)17 << 20) : ((size_t)1 << 20);
  bf16* Qr  = (bf16*)(ws + base);                       // [b][h][l][d]
  bf16* Kr  = (bf16*)(ws + base + ((size_t)8 << 20));   // [b][h][s][d]
  bf16* Vt  = (bf16*)(ws + base + ((size_t)16 << 20));  // [b][h][d][s]
  bf16* ctx = big ? Xb : (bf16*)(ws + ((size_t)25 << 20));

  tables_kernel<<<272, 256, 0, stream>>>(tab, mask, maskf);

  dim3 gp(MM / 128, EE / 64);
  if (big) {
    cvt4_kernel<<<4096, 256, 0, stream>>>(Wq, Wk, Wv, Wo, Wb);
    cvt_kernel<<<4096, 256, 0, stream>>>(query, Xb);
    projs_kernel<0><<<gp, 256, 0, stream>>>(Xb, Wb, bq, Qr, tab);
    cvt_kernel<<<4096, 256, 0, stream>>>(key, Xb);
    projs_kernel<1><<<gp, 256, 0, stream>>>(Xb, Wb + (size_t)EE * EE, bk, Kr, tab);
    cvt_kernel<<<4096, 256, 0, stream>>>(value, Xb);
    projs_kernel<2><<<gp, 256, 0, stream>>>(Xb, Wb + (size_t)2 * EE * EE, bv, Vt, tab);
  } else {
    proj_kernel<0, false, false><<<gp, 256, 0, stream>>>(query, Wq, bq, Qr, tab);
    proj_kernel<1, false, false><<<gp, 256, 0, stream>>>(key,   Wk, bk, Kr, tab);
    proj_kernel<2, false, false><<<gp, 256, 0, stream>>>(value, Wv, bv, Vt, tab);
  }

  attn_kernel<<<(LL / 128) * 2 * HH, 256, 0, stream>>>(Qr, Kr, Vt, maskf, ctx);

  if (big) projs_kernel<3><<<gp, 256, 0, stream>>>(ctx, Wb + (size_t)3 * EE * EE, bo, d_out, tab);
  else     proj_kernel<3, true, false><<<gp, 256, 0, stream>>>(ctx, Wo, bo, d_out, tab);
}

// Round 4
// 261.704 us; speedup vs baseline: 1.7280x; 1.0161x over previous
//
#include <hip/hip_runtime.h>
#include <hip/hip_bf16.h>

typedef __hip_bfloat16 bf16;
typedef short bf16x8 __attribute__((ext_vector_type(8)));   // 8 bf16 = 4 VGPRs (MFMA frag)
typedef float f32x4 __attribute__((ext_vector_type(4)));
typedef short s4 __attribute__((ext_vector_type(4)));

#define LL 2048
#define SS 2048
#define EE 1024
#define HH 16
#define HD 64
#define MM (LL * 2)   // 4096 rows (l*B+b)

static __device__ __forceinline__ short f2bs(float f) {
  bf16 h = __float2bfloat16(f);
  short u;
  __builtin_memcpy(&u, &h, 2);
  return u;
}

// pack 8 f32 -> bf16x8 and store to LDS (one ds_write_b128)
static __device__ __forceinline__ void st8(bf16* p, float4 x, float4 y) {
  bf16x8 v;
  v[0] = f2bs(x.x); v[1] = f2bs(x.y); v[2] = f2bs(x.z); v[3] = f2bs(x.w);
  v[4] = f2bs(y.x); v[5] = f2bs(y.y); v[6] = f2bs(y.z); v[7] = f2bs(y.w);
  *(bf16x8*)p = v;
}

// async global->LDS, 16B per lane. LDS dest must be wave-uniform base + lane*16.
#define GLL16(gp, lp) __builtin_amdgcn_global_load_lds(                        \
    (const __attribute__((address_space(1))) void*)(gp),                       \
    (__attribute__((address_space(3))) void*)(lp), 16, 0, 0)

// cos/sin table (blocks 0..255) + mask->float bias (blocks 256..271).
__global__ __launch_bounds__(256) void tables_kernel(
    float2* __restrict__ tab, const unsigned char* __restrict__ m,
    float* __restrict__ mf) {
  if (blockIdx.x < 256) {
    int i = blockIdx.x * 256 + threadIdx.x;   // 2048*32 entries
    int pos = i >> 5, fi = i & 31;
    float freq = expf(-(float)fi * (9.210340371976184f / 32.0f));  // 10000^(-fi/32)
    float ang = (float)pos * freq;
    float s, c;
    sincosf(ang, &s, &c);
    tab[i] = make_float2(c, s);
  } else {
    int i = (blockIdx.x - 256) * 256 + threadIdx.x;
    if (i < 2 * SS) mf[i] = m[i] ? -1e30f : 0.f;
  }
}

// 4 weight matrices (1M elems each) in one launch: grid 4096, sel = blk>>10.
__global__ __launch_bounds__(256) void cvt4_kernel(
    const float* __restrict__ s0, const float* __restrict__ s1,
    const float* __restrict__ s2, const float* __restrict__ s3,
    bf16* __restrict__ dst) {
  int sel = blockIdx.x >> 10;
  const float* src = (sel == 0) ? s0 : (sel == 1) ? s1 : (sel == 2) ? s2 : s3;
  size_t loc = ((size_t)(blockIdx.x & 1023) * 256 + threadIdx.x) * 4;
  float4 v = *(const float4*)(src + loc);
  s4 p;
  p[0] = f2bs(v.x); p[1] = f2bs(v.y); p[2] = f2bs(v.z); p[3] = f2bs(v.w);
  *(s4*)(dst + (size_t)sel * EE * EE + loc) = p;
}

// ---------------------------------------------------------------------------
// OLD direct-from-global proj (kept only for the small-ws f32 fallback path).
template<int MODE, bool XB16, bool WB16>
__global__ __launch_bounds__(256) void proj_kernel(
    const void* __restrict__ Xv, const void* __restrict__ Wv,
    const float* __restrict__ bias, void* __restrict__ dstv,
    const float2* __restrict__ tab)
{
  const int w = threadIdx.x >> 6;
  const int lane = threadIdx.x & 63;
  const int l15 = lane & 15, quad = lane >> 4;
  const int tm = blockIdx.x * 128 + w * 32;
  const int tn = blockIdx.y * 64;

  const size_t aoff0 = (size_t)(tm + l15) * EE + quad * 8;
  const size_t aoff1 = aoff0 + (size_t)16 * EE;
  const size_t woff  = (size_t)(tn + l15) * EE + quad * 8;

  f32x4 zero4 = {0.f, 0.f, 0.f, 0.f};
  f32x4 acc[2][4];
#pragma unroll
  for (int mi = 0; mi < 2; ++mi)
#pragma unroll
    for (int ni = 0; ni < 4; ++ni) acc[mi][ni] = zero4;

  for (int k0 = 0; k0 < EE; k0 += 32) {
    bf16x8 a0, a1;
    if (XB16 || MODE == 3) {
      const bf16* Xb = (const bf16*)Xv;
      a0 = *(const bf16x8*)(Xb + aoff0 + k0);
      a1 = *(const bf16x8*)(Xb + aoff1 + k0);
    } else {
      const float* Xf = (const float*)Xv;
#pragma unroll
      for (int j = 0; j < 8; ++j) a0[j] = f2bs(Xf[aoff0 + k0 + j]);
#pragma unroll
      for (int j = 0; j < 8; ++j) a1[j] = f2bs(Xf[aoff1 + k0 + j]);
    }
#pragma unroll
    for (int ni = 0; ni < 4; ++ni) {
      bf16x8 bv;
      if (WB16) {
        const bf16* Wb = (const bf16*)Wv;
        bv = *(const bf16x8*)(Wb + woff + (size_t)ni * 16 * EE + k0);
      } else {
        const float* Wf = (const float*)Wv;
#pragma unroll
        for (int j = 0; j < 8; ++j) bv[j] = f2bs(Wf[woff + (size_t)ni * 16 * EE + k0 + j]);
      }
      acc[0][ni] = __builtin_amdgcn_mfma_f32_16x16x32_bf16(a0, bv, acc[0][ni], 0, 0, 0);
      acc[1][ni] = __builtin_amdgcn_mfma_f32_16x16x32_bf16(a1, bv, acc[1][ni], 0, 0, 0);
    }
  }

  float bz[4];
#pragma unroll
  for (int ni = 0; ni < 4; ++ni) bz[ni] = bias[tn + ni * 16 + l15];

#pragma unroll
  for (int mi = 0; mi < 2; ++mi) {
#pragma unroll
    for (int ni = 0; ni < 4; ++ni) {
      const int n = tn + ni * 16 + l15;
#pragma unroll
      for (int r = 0; r < 4; ++r) {
        const int m = tm + mi * 16 + quad * 4 + r;
        float v = acc[mi][ni][r] + bz[ni];
        if (MODE <= 1) {
          float other = __shfl_xor(v, 1, 64);        // pair element (n^1) is in lane^1
          int pos = m >> 1, b = m & 1, d = n & 63, h = n >> 6;
          float2 cs = tab[pos * 32 + (d >> 1)];
          float rv = (d & 1) ? (other * cs.y + v * cs.x) : (v * cs.x - other * cs.y);
          ((bf16*)dstv)[((size_t)(b * HH + h) * LL + pos) * HD + d] = __float2bfloat16(rv);
        } else if (MODE == 2) {
          int pos = m >> 1, b = m & 1, d = n & 63, h = n >> 6;
          ((bf16*)dstv)[((size_t)(b * HH + h) * HD + d) * SS + pos] = __float2bfloat16(v);
        } else {
          ((float*)dstv)[(size_t)m * EE + n] = v;
        }
      }
    }
  }
}

// ---------------------------------------------------------------------------
// ROUND-4: fused Q+K+V projection, one dispatch, grid 1536 (6 blocks/CU issued,
// 4 resident) — 3x the independent barrier groups per CU vs round 3's 2.
// Round-2 vs round-3 showed the projs wall (~43 µs) is latency x insufficient
// concurrency, not schedule structure: no pipe is near a throughput ceiling.
// Tile 128m x 64n, BK=32; A reg-staged DIRECTLY from f32 inputs (inline cvt,
// T14 split: loads issued at top of iter, cvt+ds_write after compute) — kills
// the 3 cvt dispatches and fits fusion in the 41 MB workspace. B via gll from
// pre-converted Wb. 64 B LDS rows: (row*16+chunk*4) bank map tiles all 32
// banks evenly -> conflict-free WITHOUT swizzle (rows alternate bank halves).
// z = blockIdx.x>>9 selects matrix; epilogue branches are block-uniform.
__global__ __launch_bounds__(256, 4) void qkv_kernel(
    const float* __restrict__ Xq, const float* __restrict__ Xk,
    const float* __restrict__ Xv, const bf16* __restrict__ Wb,
    const float* __restrict__ bq, const float* __restrict__ bk,
    const float* __restrict__ bv, bf16* __restrict__ Qr,
    bf16* __restrict__ Kr, bf16* __restrict__ Vt,
    const float2* __restrict__ tab)
{
  __shared__ __align__(16) bf16 As[2][128 * 32];   // 8 KB per buf
  __shared__ __align__(16) bf16 Bs[2][64 * 32];    // 4 KB per buf

  const int tid = threadIdx.x;
  const int w = tid >> 6;
  const int lane = tid & 63;
  const int l15 = lane & 15, quad = lane >> 4;
  const int id = blockIdx.x;
  const int z = id >> 9;                 // 0=Q 1=K 2=V
  const int g = id & 511;
  const int tmb = (g & 31) * 128;        // same-A blocks (y varies) land on same XCD
  const int tn  = (g >> 5) * 64;

  const float* Xf = (z == 0) ? Xq : (z == 1) ? Xk : Xv;
  const bf16* Wm  = Wb + (size_t)z * EE * EE;
  const float* bias = (z == 0) ? bq : (z == 1) ? bk : bv;
  bf16* dst = (z == 0) ? Qr : (z == 1) ? Kr : Vt;

  // A staging map: thread -> rows ar and ar+64, k-chunk ac (8 f32 = 2 float4).
  const int ar = tid >> 2;               // 0..63
  const int ac = (tid & 3) * 8;
  const float* gA0 = Xf + (size_t)(tmb + ar) * EE + ac;
  const float* gA1 = gA0 + (size_t)64 * EE;
  // B staging: 1 gll/wave: rows tn+16w.. , row = 16w + (lane>>2), chunk lane&3
  const bf16* gB = Wm + (size_t)(tn + w * 16 + (lane >> 2)) * EE + (lane & 3) * 8;

  f32x4 zero4 = {0.f, 0.f, 0.f, 0.f};
  f32x4 acc[2][4];
#pragma unroll
  for (int mi = 0; mi < 2; ++mi)
#pragma unroll
    for (int ni = 0; ni < 4; ++ni) acc[mi][ni] = zero4;

  {  // prologue: stage tile 0
    float4 a00 = *(const float4*)(gA0);
    float4 a01 = *(const float4*)(gA0 + 4);
    float4 a10 = *(const float4*)(gA1);
    float4 a11 = *(const float4*)(gA1 + 4);
    GLL16(gB, (bf16*)&Bs[0][w * 16 * 32] + lane * 8);
    st8(&As[0][ar * 32 + ac], a00, a01);
    st8(&As[0][(64 + ar) * 32 + ac], a10, a11);
  }
  __syncthreads();

  for (int t = 0; t < 32; ++t) {
    const int cur = t & 1;
    float4 a00, a01, a10, a11;
    if (t < 31) {                        // issue next-tile loads EARLY (T14)
      const int k0 = (t + 1) * 32;
      a00 = *(const float4*)(gA0 + k0);
      a01 = *(const float4*)(gA0 + k0 + 4);
      a10 = *(const float4*)(gA1 + k0);
      a11 = *(const float4*)(gA1 + k0 + 4);
      GLL16(gB + k0, (bf16*)&Bs[cur ^ 1][w * 16 * 32] + lane * 8);
    }
    // compute current tile: 8 MFMA/wave
    bf16x8 af0 = *(const bf16x8*)(&As[cur][(w * 32 + l15) * 32 + quad * 8]);
    bf16x8 af1 = *(const bf16x8*)(&As[cur][(w * 32 + 16 + l15) * 32 + quad * 8]);
#pragma unroll
    for (int ni = 0; ni < 4; ++ni) {
      bf16x8 bfr = *(const bf16x8*)(&Bs[cur][(ni * 16 + l15) * 32 + quad * 8]);
      acc[0][ni] = __builtin_amdgcn_mfma_f32_16x16x32_bf16(af0, bfr, acc[0][ni], 0, 0, 0);
      acc[1][ni] = __builtin_amdgcn_mfma_f32_16x16x32_bf16(af1, bfr, acc[1][ni], 0, 0, 0);
    }
    if (t < 31) {                        // write-late: cvt lands after compute
      st8(&As[cur ^ 1][ar * 32 + ac], a00, a01);
      st8(&As[cur ^ 1][(64 + ar) * 32 + ac], a10, a11);
    }
    __syncthreads();                     // drains gll (B ready) + ds_writes + reads
  }

  float bz[4];
#pragma unroll
  for (int ni = 0; ni < 4; ++ni) bz[ni] = bias[tn + ni * 16 + l15];

#pragma unroll
  for (int mi = 0; mi < 2; ++mi) {
#pragma unroll
    for (int ni = 0; ni < 4; ++ni) {
      const int n = tn + ni * 16 + l15;
#pragma unroll
      for (int r = 0; r < 4; ++r) {
        const int m = tmb + w * 32 + mi * 16 + quad * 4 + r;
        float v = acc[mi][ni][r] + bz[ni];
        if (z <= 1) {                    // RoPE epilogue (Q, K)
          float other = __shfl_xor(v, 1, 64);   // pair element (n^1) is in lane^1
          int pos = m >> 1, b = m & 1, d = n & 63, h = n >> 6;
          float2 cs = tab[pos * 32 + (d >> 1)];
          float rv = (d & 1) ? (other * cs.y + v * cs.x) : (v * cs.x - other * cs.y);
          dst[((size_t)(b * HH + h) * LL + pos) * HD + d] = __float2bfloat16(rv);
        } else {                         // V: store transposed [b][h][d][pos]
          int pos = m >> 1, b = m & 1, d = n & 63, h = n >> 6;
          dst[((size_t)(b * HH + h) * HD + d) * SS + pos] = __float2bfloat16(v);
        }
      }
    }
  }
}

// ---------------------------------------------------------------------------
// ROUND-4 O-projection: tile 64m x 64n, BK=32, grid (64,16)=1024 = 4 blocks/CU
// (vs 2 before). A (ctx, bf16) and B both gll-staged; 16 KB LDS; same
// no-swizzle-needed 64 B-row layout. Per wave: 16m x 64n, 4 MFMA/K-step.
__global__ __launch_bounds__(256) void projo_kernel(
    const bf16* __restrict__ X, const bf16* __restrict__ W,
    const float* __restrict__ bias, float* __restrict__ dst)
{
  __shared__ __align__(16) bf16 As[2][64 * 32];    // 4 KB per buf
  __shared__ __align__(16) bf16 Bs[2][64 * 32];    // 4 KB per buf

  const int tid = threadIdx.x;
  const int w = tid >> 6;
  const int lane = tid & 63;
  const int l15 = lane & 15, quad = lane >> 4;
  const int tmb = blockIdx.x * 64;
  const int tn  = blockIdx.y * 64;

  // staging: 1 gll each for A and B per wave: row = 16w + (lane>>2), chunk lane&3
  const bf16* gA = X + (size_t)(tmb + w * 16 + (lane >> 2)) * EE + (lane & 3) * 8;
  const bf16* gB = W + (size_t)(tn  + w * 16 + (lane >> 2)) * EE + (lane & 3) * 8;

  f32x4 zero4 = {0.f, 0.f, 0.f, 0.f};
  f32x4 acc[4];
#pragma unroll
  for (int ni = 0; ni < 4; ++ni) acc[ni] = zero4;

  GLL16(gA, (bf16*)&As[0][w * 16 * 32] + lane * 8);
  GLL16(gB, (bf16*)&Bs[0][w * 16 * 32] + lane * 8);
  __syncthreads();

  for (int t = 0; t < 32; ++t) {
    const int cur = t & 1;
    if (t < 31) {
      const int k0 = (t + 1) * 32;
      GLL16(gA + k0, (bf16*)&As[cur ^ 1][w * 16 * 32] + lane * 8);
      GLL16(gB + k0, (bf16*)&Bs[cur ^ 1][w * 16 * 32] + lane * 8);
    }
    bf16x8 af = *(const bf16x8*)(&As[cur][(w * 16 + l15) * 32 + quad * 8]);
#pragma unroll
    for (int ni = 0; ni < 4; ++ni) {
      bf16x8 bfr = *(const bf16x8*)(&Bs[cur][(ni * 16 + l15) * 32 + quad * 8]);
      acc[ni] = __builtin_amdgcn_mfma_f32_16x16x32_bf16(af, bfr, acc[ni], 0, 0, 0);
    }
    __syncthreads();
  }

  float bz[4];
#pragma unroll
  for (int ni = 0; ni < 4; ++ni) bz[ni] = bias[tn + ni * 16 + l15];

#pragma unroll
  for (int ni = 0; ni < 4; ++ni) {
    const int n = tn + ni * 16 + l15;
#pragma unroll
    for (int r = 0; r < 4; ++r) {
      const int m = tmb + w * 16 + quad * 4 + r;
      dst[(size_t)m * EE + n] = acc[ni][r] + bz[ni];
    }
  }
}

// ---------------------------------------------------------------------------
// Flash attention — BYTE-IDENTICAL to rounds 2/3 (67.5-69.8 µs, proven).
__global__ __launch_bounds__(256) void attn_kernel(
    const bf16* __restrict__ Qr, const bf16* __restrict__ Kr,
    const bf16* __restrict__ Vt, const float* __restrict__ maskf,
    bf16* __restrict__ ctx)
{
  __shared__ __align__(16) bf16 Ks[2][64 * 64];       // 16 KB: [buf][s][d]
  __shared__ __align__(16) bf16 Vs[2][64 * 64];       // 16 KB: [buf][d][s]
  __shared__ __align__(16) short Plds[4][32][56];     // 14 KB: [wave][q][s str 56]

  const int w = threadIdx.x >> 6;
  const int lane = threadIdx.x & 63;
  const int l15 = lane & 15, quad = lane >> 4;
  const int id = blockIdx.x;
  const int bh = id & 31;             // XCD = bh % 8
  const int qt = id >> 5;             // 0..15
  const int b = bh >> 4, h = bh & 15;
  const int q0 = qt * 128 + w * 32;

  const bf16* Qbh = Qr + (size_t)bh * LL * HD;
  const bf16* Kbh = Kr + (size_t)bh * SS * HD;
  const bf16* Vbh = Vt + (size_t)bh * HD * SS;
  const float* mrow = maskf + b * SS;

  bf16x8 qf[2][2];
#pragma unroll
  for (int mi = 0; mi < 2; ++mi) {
    const bf16* qp = Qbh + (size_t)(q0 + mi * 16 + l15) * HD + quad * 8;
    qf[mi][0] = *(const bf16x8*)(qp);
    qf[mi][1] = *(const bf16x8*)(qp + 32);
  }

  const int srow = lane >> 3;                     // 0..7
  const int gswz = ((lane & 7) ^ srow) * 8;       // source chunk, elems
  const int kswz0 = ((quad    ) ^ (l15 & 7)) * 8;
  const int kswz1 = ((quad + 4) ^ (l15 & 7)) * 8;

#define STAGE(buf, S0) {                                                       \
    _Pragma("unroll")                                                          \
    for (int i = 0; i < 2; ++i) {                                              \
      const int rb = w * 16 + i * 8;                                           \
      GLL16(Kbh + (size_t)((S0) + rb + srow) * HD + gswz,                      \
            (bf16*)&Ks[buf][rb * 64] + lane * 8);                              \
      GLL16(Vbh + (size_t)(rb + srow) * SS + (S0) + gswz,                      \
            (bf16*)&Vs[buf][rb * 64] + lane * 8);                              \
    }                                                                          \
  }

  f32x4 zero4 = {0.f, 0.f, 0.f, 0.f};
  f32x4 o[2][4];
#pragma unroll
  for (int mi = 0; mi < 2; ++mi)
#pragma unroll
    for (int t = 0; t < 4; ++t) o[mi][t] = zero4;
  float ps0 = 0.f, ps1 = 0.f;

  STAGE(0, 0);
  __syncthreads();

  for (int t = 0; t < SS / 64; ++t) {
    const int s0 = t * 64;
    const int cur = t & 1;
    if (t + 1 < SS / 64) STAGE(cur ^ 1, s0 + 64);   // prefetch next 64-s tile

#pragma unroll
    for (int ss = 0; ss < 2; ++ss) {
      const bf16* Kb = &Ks[cur][ss * 32 * 64];
      bf16x8 kf00 = *(const bf16x8*)(Kb + (l15)      * 64 + kswz0);
      bf16x8 kf01 = *(const bf16x8*)(Kb + (l15)      * 64 + kswz1);
      bf16x8 kf10 = *(const bf16x8*)(Kb + (16 + l15) * 64 + kswz0);
      bf16x8 kf11 = *(const bf16x8*)(Kb + (16 + l15) * 64 + kswz1);
      bf16x8 vf[4];
#pragma unroll
      for (int tt = 0; tt < 4; ++tt)
        vf[tt] = *(const bf16x8*)(&Vs[cur][0] + (tt * 16 + l15) * 64 +
                                  (((ss * 4 + quad) ^ (l15 & 7)) * 8));
      f32x4 mv0 = *(const f32x4*)(mrow + s0 + ss * 32 + quad * 4);
      f32x4 mv1 = *(const f32x4*)(mrow + s0 + ss * 32 + 16 + quad * 4);

#pragma unroll
      for (int mi = 0; mi < 2; ++mi) {
        f32x4 sc0 = zero4, sc1 = zero4;
        sc0 = __builtin_amdgcn_mfma_f32_16x16x32_bf16(kf00, qf[mi][0], sc0, 0, 0, 0);
        sc0 = __builtin_amdgcn_mfma_f32_16x16x32_bf16(kf01, qf[mi][1], sc0, 0, 0, 0);
        sc1 = __builtin_amdgcn_mfma_f32_16x16x32_bf16(kf10, qf[mi][0], sc1, 0, 0, 0);
        sc1 = __builtin_amdgcn_mfma_f32_16x16x32_bf16(kf11, qf[mi][1], sc1, 0, 0, 0);
        s4 pk0, pk1;
#pragma unroll
        for (int r = 0; r < 4; ++r) {
          float p = __expf(sc0[r] * 0.125f + mv0[r]);
          if (mi == 0) ps0 += p; else ps1 += p;
          pk0[r] = f2bs(p);
        }
#pragma unroll
        for (int r = 0; r < 4; ++r) {
          float p = __expf(sc1[r] * 0.125f + mv1[r]);
          if (mi == 0) ps0 += p; else ps1 += p;
          pk1[r] = f2bs(p);
        }
        *(s4*)&Plds[w][mi * 16 + l15][quad * 4] = pk0;
        *(s4*)&Plds[w][mi * 16 + l15][16 + quad * 4] = pk1;
      }
      asm volatile("" ::: "memory");   // all P-writes before cross-lane P-read
      bf16x8 pf0 = *(const bf16x8*)&Plds[w][l15][quad * 8];
      bf16x8 pf1 = *(const bf16x8*)&Plds[w][16 + l15][quad * 8];
#pragma unroll
      for (int tt = 0; tt < 4; ++tt) {
        o[0][tt] = __builtin_amdgcn_mfma_f32_16x16x32_bf16(pf0, vf[tt], o[0][tt], 0, 0, 0);
        o[1][tt] = __builtin_amdgcn_mfma_f32_16x16x32_bf16(pf1, vf[tt], o[1][tt], 0, 0, 0);
      }
      asm volatile("" ::: "memory");   // P-reads done before next subtile overwrites
    }
    __syncthreads();   // drains gll (next buf ready) + all waves done with cur
  }
#undef STAGE

  float lv0 = ps0; lv0 += __shfl_xor(lv0, 16, 64); lv0 += __shfl_xor(lv0, 32, 64);
  float lv1 = ps1; lv1 += __shfl_xor(lv1, 16, 64); lv1 += __shfl_xor(lv1, 32, 64);

#pragma unroll
  for (int mi = 0; mi < 2; ++mi) {
#pragma unroll
    for (int r = 0; r < 4; ++r) {
      float lv = (mi == 0) ? lv0 : lv1;
      float li = __shfl(lv, quad * 4 + r, 64);   // denom for q-row quad*4+r
      float inv = 1.0f / li;
      int q = q0 + mi * 16 + quad * 4 + r;
#pragma unroll
      for (int t = 0; t < 4; ++t) {
        float val = o[mi][t][r] * inv;
        ctx[(size_t)(q * 2 + b) * EE + (size_t)h * 64 + t * 16 + l15] = __float2bfloat16(val);
      }
    }
  }
}

extern "C" void kernel_launch(void* const* d_in, const int* in_sizes, int n_in,
                              void* d_out, int out_size, void* d_ws, size_t ws_size,
                              hipStream_t stream) {
  const float* query = (const float*)d_in[0];
  const float* key   = (const float*)d_in[1];
  const float* value = (const float*)d_in[2];
  const unsigned char* mask = (const unsigned char*)d_in[3];
  const float* Wq = (const float*)d_in[4];
  const float* bq = (const float*)d_in[5];
  const float* Wk = (const float*)d_in[6];
  const float* bk = (const float*)d_in[7];
  const float* Wv = (const float*)d_in[8];
  const float* bv = (const float*)d_in[9];
  const float* Wo = (const float*)d_in[10];
  const float* bo = (const float*)d_in[11];

  char* ws = (char*)d_ws;
  const bool big = ws_size >= ((size_t)41 << 20);

  // Layout A (small, <=33 MB): tab@0 | Qr@1M | Kr@9M | Vt@17M | ctx@25M
  // Layout B (big, 41 MB): tab@0 | Wb@1M (8 MB) | Qr@9M | Kr@17M | Vt@25M | ctx@33M
  float2* tab   = (float2*)ws;                          // 512 KB
  float*  maskf = (float*)(ws + (512 << 10));           // 16 KB (inside tab's MB)
  bf16* Wb = (bf16*)(ws + ((size_t)1 << 20));           // big only: 4 x 1M bf16
  size_t base = big ? ((size_t)9 << 20) : ((size_t)1 << 20);
  bf16* Qr  = (bf16*)(ws + base);                       // [b][h][l][d]
  bf16* Kr  = (bf16*)(ws + base + ((size_t)8 << 20));   // [b][h][s][d]
  bf16* Vt  = (bf16*)(ws + base + ((size_t)16 << 20));  // [b][h][d][s]
  bf16* ctx = (bf16*)(ws + base + ((size_t)24 << 20));

  tables_kernel<<<272, 256, 0, stream>>>(tab, mask, maskf);

  if (big) {
    cvt4_kernel<<<4096, 256, 0, stream>>>(Wq, Wk, Wv, Wo, Wb);
    qkv_kernel<<<1536, 256, 0, stream>>>(query, key, value, Wb, bq, bk, bv,
                                         Qr, Kr, Vt, tab);
  } else {
    dim3 gp(MM / 128, EE / 64);
    proj_kernel<0, false, false><<<gp, 256, 0, stream>>>(query, Wq, bq, Qr, tab);
    proj_kernel<1, false, false><<<gp, 256, 0, stream>>>(key,   Wk, bk, Kr, tab);
    proj_kernel<2, false, false><<<gp, 256, 0, stream>>>(value, Wv, bv, Vt, tab);
  }

  attn_kernel<<<(LL / 128) * 2 * HH, 256, 0, stream>>>(Qr, Kr, Vt, maskf, ctx);

  if (big) {
    dim3 go(MM / 64, EE / 64);
    projo_kernel<<<go, 256, 0, stream>>>(ctx, Wb + (size_t)3 * EE * EE, bo, (float*)d_out);
  } else {
    dim3 gp(MM / 128, EE / 64);
    proj_kernel<3, true, false><<<gp, 256, 0, stream>>>(ctx, Wo, bo, d_out, tab);
  }
}